// Round 6
// baseline (179.285 us; speedup 1.0000x reference)
//
#include <hip/hip_runtime.h>

#define R 192
#define BATCH 1024
#define NWORDS (R * 6)          // 192 rows x 6 u32 bit-words
#define MAIN_BLOCKS (2 * BATCH) // 2 stripes x 1024 batches

// ws layout (floats):
//   ws[0]=overlap  ws[1]=adj  ws[2]=mseP  ws[3]=mseS  ws[4]=ticket(u32)  [zeroed by prep]
//   ws[8 ..]      : u32 mask[192][6], triu-baked: bit j set iff j>i && adj[i][j]>0
#define MASK_OFF_W 8

// Prep: zero accumulators+ticket, build triu-baked bitmask via ballot.
// R=192 is a multiple of 32, so word e>>5 == i*6 + j/32 exactly.
__global__ __launch_bounds__(256) void prep_kernel(
    const int* __restrict__ adj, float* __restrict__ ws)
{
    unsigned int* bits = (unsigned int*)(ws + MASK_OFF_W);
    const int e = blockIdx.x * 256 + threadIdx.x;   // 0 .. R*R-1
    if (e < 8) ws[e] = 0.0f;
    if (e >= R * R) return;
    const int i = e / R;
    const int j = e - i * R;
    const unsigned long long m = __ballot((adj[e] > 0) && (j > i));
    const int lane = e & 63;
    if (lane == 0)  bits[e >> 5] = (unsigned int)m;
    if (lane == 32) bits[e >> 5] = (unsigned int)(m >> 32);
}

// Main: one block per (stripe, batch). All operands in LDS, inputs read
// directly from pristine d_in. 2048 blocks -> 8 blocks/CU target.
__global__ __launch_bounds__(256, 6) void main_kernel(
    const float* __restrict__ pos, const float* __restrict__ siz,
    const float* __restrict__ tpos, const float* __restrict__ tsiz,
    float* __restrict__ ws, float* __restrict__ out)
{
    __shared__ float4 room[R];          // x, y, x+w, y+h
    __shared__ float2 ctr2[R];          // (2*cx, 2*cy) = (x + (x+w), y + (y+h))
    __shared__ unsigned int smask[NWORDS];
    __shared__ float wsum[4][4];
    __shared__ int is_last;

    const int s   = blockIdx.x;         // 0/1 stripe
    const int b   = blockIdx.y;
    const int tid = threadIdx.x;

    const unsigned int* gmask = (const unsigned int*)(ws + MASK_OFF_W);

    float mp = 0.0f, ms = 0.0f;

    // ---- stage ----
    if (tid < R) {
        const float2 p  = ((const float2*)pos)[(size_t)b * R + tid];
        const float2 sz = ((const float2*)siz)[(size_t)b * R + tid];
        const float xw = p.x + sz.x;
        const float yh = p.y + sz.y;
        room[tid] = make_float4(p.x, p.y, xw, yh);
        ctr2[tid] = make_float2(p.x + xw, p.y + yh);
        if (s == 0) {   // fused MSE on stripe 0 only
            const float2 tp = ((const float2*)tpos)[(size_t)b * R + tid];
            const float2 ts = ((const float2*)tsiz)[(size_t)b * R + tid];
            float dpx = p.x - tp.x, dpy = p.y - tp.y;
            float dsx = sz.x - ts.x, dsy = sz.y - ts.y;
            mp = dpx * dpx + dpy * dpy;
            ms = dsx * dsx + dsy * dsy;
        }
    }
    for (int w = tid; w < NWORDS; w += 256) smask[w] = gmask[w];
    __syncthreads();

    // ---- pair loop: 16x16 tiles, tj-parity stripes; diagonal peeled to s==1 ----
    const int li = tid >> 4;            // 0..15
    const int lj = tid & 15;            // 0..15
    float ov = 0.0f, ad = 0.0f;

    for (int ti = 0; ti < 12; ++ti) {
        const int i = ti * 16 + li;
        const float4 ri = room[i];
        const float2 ci = ctr2[i];
        const unsigned int* rowbits = &smask[i * 6];

        for (int tj = ti + 1 + s; tj < 12; tj += 2) {
            const int j = tj * 16 + lj;
            const float4 rj = room[j];
            const float2 cj = ctr2[j];
            const unsigned int mw = rowbits[tj >> 1];

            float ow = fminf(ri.z, rj.z) - fmaxf(ri.x, rj.x);
            float oh = fminf(ri.w, rj.w) - fmaxf(ri.y, rj.y);
            ov = fmaf(fmaxf(ow, 0.0f), fmaxf(oh, 0.0f), ov);

            const unsigned int bit = (mw >> (((tj & 1) << 4) + lj)) & 1u;
            float dx = ci.x - cj.x;          // 2*dx
            float dy = ci.y - cj.y;          // 2*dy
            float q  = fmaf(dx, dx, dy * dy);
            float r2 = __builtin_amdgcn_sqrtf(q);   // 2*dist
            ad = fmaf(bit ? 0.5f : 0.0f, r2, ad);
        }

        if (s == 1) {   // diagonal tile: tj == ti; mask bit already 0 for j<=i
            const int j = ti * 16 + lj;
            const float4 rj = room[j];
            const float2 cj = ctr2[j];
            const unsigned int mw = rowbits[ti >> 1];

            float ow = fminf(ri.z, rj.z) - fmaxf(ri.x, rj.x);
            float oh = fminf(ri.w, rj.w) - fmaxf(ri.y, rj.y);
            float area = fmaxf(ow, 0.0f) * fmaxf(oh, 0.0f);
            ov += (i < j) ? area : 0.0f;

            const unsigned int bit = (mw >> (((ti & 1) << 4) + lj)) & 1u;
            float dx = ci.x - cj.x;
            float dy = ci.y - cj.y;
            float q  = fmaf(dx, dx, dy * dy);
            float r2 = __builtin_amdgcn_sqrtf(q);
            ad = fmaf(bit ? 0.5f : 0.0f, r2, ad);
        }
    }

    // ---- block reduce + global accumulate + ticket ----
    for (int off = 32; off > 0; off >>= 1) {
        ov += __shfl_down(ov, off);
        ad += __shfl_down(ad, off);
        mp += __shfl_down(mp, off);
        ms += __shfl_down(ms, off);
    }
    const int wid = tid >> 6, lane = tid & 63;
    if (lane == 0) {
        wsum[wid][0] = ov; wsum[wid][1] = ad;
        wsum[wid][2] = mp; wsum[wid][3] = ms;
    }
    __syncthreads();
    if (tid == 0) {
        atomicAdd(&ws[0], wsum[0][0] + wsum[1][0] + wsum[2][0] + wsum[3][0]);
        atomicAdd(&ws[1], wsum[0][1] + wsum[1][1] + wsum[2][1] + wsum[3][1]);
        if (s == 0) {
            atomicAdd(&ws[2], wsum[0][2] + wsum[1][2] + wsum[2][2] + wsum[3][2]);
            atomicAdd(&ws[3], wsum[0][3] + wsum[1][3] + wsum[2][3] + wsum[3][3]);
        }
        __threadfence();
        unsigned int old = atomicAdd((unsigned int*)(ws + 4), 1u);
        is_last = (old == (unsigned int)(MAIN_BLOCKS - 1)) ? 1 : 0;
    }
    __syncthreads();

    // ---- fused finalize ----
    if (is_last && tid == 0) {
        float ovT  = atomicAdd(&ws[0], 0.0f);
        float adT  = atomicAdd(&ws[1], 0.0f);
        float mseP = atomicAdd(&ws[2], 0.0f);
        float mseS = atomicAdd(&ws[3], 0.0f);
        const float invN = 1.0f / (float)(BATCH * R * 2);
        const float invB = 1.0f / (float)BATCH;
        float pos_loss  = mseP * invN;
        float size_loss = mseS * invN;
        float overlap   = ovT * invB;
        float adjl      = adT * invB;
        out[0] = pos_loss + size_loss + 0.5f * overlap + 0.3f * adjl;
        out[1] = pos_loss;
        out[2] = size_loss;
        out[3] = overlap;
        out[4] = adjl;
    }
}

extern "C" void kernel_launch(void* const* d_in, const int* in_sizes, int n_in,
                              void* d_out, int out_size, void* d_ws, size_t ws_size,
                              hipStream_t stream) {
    const float* pos  = (const float*)d_in[0];
    const float* siz  = (const float*)d_in[1];
    const float* tpos = (const float*)d_in[2];
    const float* tsiz = (const float*)d_in[3];
    const int*   adj  = (const int*)d_in[4];
    float* ws  = (float*)d_ws;
    float* out = (float*)d_out;

    hipLaunchKernelGGL(prep_kernel, dim3((R * R + 255) / 256), dim3(256), 0, stream,
                       adj, ws);
    hipLaunchKernelGGL(main_kernel, dim3(2, BATCH), dim3(256), 0, stream,
                       pos, siz, tpos, tsiz, ws, out);
}